// Round 1
// baseline (836.807 us; speedup 1.0000x reference)
//
#include <hip/hip_runtime.h>
#include <math.h>

#define Hh 128
#define Ww 128
#define HW (128*128)

// ---------------- weight transposes ----------------
// conv weights [Cout][Cin][3][3] -> [Cin][9][Cout]  (uniform contiguous scalar loads)
__global__ __launch_bounds__(256) void wtrans_conv_k(const float* __restrict__ w,
                                                     float* __restrict__ wt,
                                                     int Cout, int Cin) {
  int idx = blockIdx.x * 256 + threadIdx.x;
  int total = Cout * Cin * 9;
  if (idx >= total) return;
  int co = idx / (Cin * 9);
  int r  = idx % (Cin * 9);
  int ci = r / 9, k = r % 9;
  wt[((size_t)ci * 9 + k) * Cout + co] = w[idx];
}

// dcn weight [64][64][3][3] -> [dg][k][c][64]   (cin = dg*4+c)
__global__ __launch_bounds__(256) void wtrans_dcn_k(const float* __restrict__ w,
                                                    float* __restrict__ wt) {
  int idx = blockIdx.x * 256 + threadIdx.x;
  if (idx >= 64 * 64 * 9) return;
  int co = idx / 576;
  int r  = idx % 576;
  int ci = r / 9, k = r % 9;
  int dg = ci >> 2, c = ci & 3;
  wt[(((size_t)dg * 9 + k) * 4 + c) * 64 + co] = w[idx];
}

// x [B][64][H][W] -> xt [B][16][H][W][4]  (float4 per (dg,pixel))
__global__ __launch_bounds__(256) void xtrans_k(const float* __restrict__ x,
                                                float* __restrict__ xt, int B) {
  int idx = blockIdx.x * 256 + threadIdx.x;
  int total = B * 16 * HW;
  if (idx >= total) return;
  int b = idx / (16 * HW);
  int r = idx % (16 * HW);
  int dg = r / HW, p = r % HW;
  const float* xb = x + ((size_t)b * 64 + dg * 4) * HW + p;
  float4 v;
  v.x = xb[0]; v.y = xb[HW]; v.z = xb[2 * HW]; v.w = xb[3 * HW];
  ((float4*)xt)[idx] = v;
}

// ---------------- conv 3x3, pad 1 ----------------
// EPI: 0 = leaky relu, 2 = offset/mask transform (conv4)
template<int CIN, int CSTEP, int EPI>
__global__ __launch_bounds__(256) void conv3x3_k(
    const float* __restrict__ in, const float* __restrict__ wt,
    const float* __restrict__ bias, float* __restrict__ out,
    float* __restrict__ out2, const float* __restrict__ flow,
    int Cout, int cgroups)
{
  __shared__ float lds[CSTEP][18 * 18];
  const int tx = threadIdx.x, ty = threadIdx.y;
  const int tid = ty * 16 + tx;
  const int bz = blockIdx.z;
  const int b = bz / cgroups, cg = bz % cgroups;
  const int x0 = blockIdx.x * 16 - 1, y0 = blockIdx.y * 16 - 1;
  const int xx = blockIdx.x * 16 + tx, yy = blockIdx.y * 16 + ty;
  const float* inb = in + (size_t)b * CIN * HW;

  float acc[16];
  #pragma unroll
  for (int i = 0; i < 16; i++) acc[i] = 0.f;

  for (int c0 = 0; c0 < CIN; c0 += CSTEP) {
    __syncthreads();
    for (int i = tid; i < CSTEP * 324; i += 256) {
      int ci = i / 324, r = i % 324;
      int ry = r / 18, rx = r % 18;
      int gy = y0 + ry, gx = x0 + rx;
      float v = 0.f;
      if (gy >= 0 && gy < Hh && gx >= 0 && gx < Ww)
        v = inb[(size_t)(c0 + ci) * HW + gy * Ww + gx];
      lds[ci][r] = v;
    }
    __syncthreads();
    for (int ci = 0; ci < CSTEP; ++ci) {
      float v[9];
      #pragma unroll
      for (int t = 0; t < 3; t++)
        #pragma unroll
        for (int s = 0; s < 3; s++)
          v[t * 3 + s] = lds[ci][(ty + t) * 18 + tx + s];
      const float* wp = wt + (size_t)(c0 + ci) * 9 * Cout + cg * 16;
      #pragma unroll
      for (int k = 0; k < 9; k++) {
        float vk = v[k];
        #pragma unroll
        for (int co = 0; co < 16; co++)
          acc[co] = fmaf(vk, wp[(size_t)k * Cout + co], acc[co]);
      }
    }
  }

  const int p = yy * Ww + xx;
  if (EPI == 0) {
    #pragma unroll
    for (int co = 0; co < 16; co++) {
      int c = cg * 16 + co;
      float v = acc[co] + bias[c];
      v = (v >= 0.f) ? v : 0.1f * v;
      out[((size_t)b * Cout + c) * HW + p] = v;
    }
  } else {
    float fl0 = flow[((size_t)b * 2 + 0) * HW + p];
    float fl1 = flow[((size_t)b * 2 + 1) * HW + p];
    #pragma unroll
    for (int co = 0; co < 16; co++) {
      int c = cg * 16 + co;
      float v = acc[co] + bias[c];
      if (c < 288) {
        // offset: 10*tanh(v) + tiled reversed flow (even ch -> flow[1], odd -> flow[0])
        float o = 10.f * tanhf(v) + ((c & 1) ? fl0 : fl1);
        out[((size_t)b * 288 + c) * HW + p] = o;
      } else {
        out2[((size_t)b * 144 + (c - 288)) * HW + p] = 1.f / (1.f + expf(-v));
      }
    }
  }
}

// ---------------- modulated deformable conv ----------------
__global__ __launch_bounds__(256) void dcn_k(
    const float* __restrict__ xt, const float* __restrict__ off,
    const float* __restrict__ msk, const float* __restrict__ wt,
    const float* __restrict__ bias, float* __restrict__ out)
{
  const int tx = threadIdx.x, ty = threadIdx.y;
  const int b = blockIdx.z >> 2, cog = blockIdx.z & 3;
  const int x = blockIdx.x * 16 + tx, y = blockIdx.y * 16 + ty;
  const int p = y * Ww + x;
  const float* offb = off + (size_t)b * 288 * HW + p;
  const float* mb   = msk + (size_t)b * 144 * HW + p;

  float acc[16];
  #pragma unroll
  for (int i = 0; i < 16; i++) acc[i] = 0.f;

  for (int dg = 0; dg < 16; ++dg) {
    const float4* xp4 = (const float4*)xt + (size_t)(b * 16 + dg) * HW;
    #pragma unroll
    for (int k = 0; k < 9; k++) {
      float dyv = offb[(size_t)(dg * 18 + k * 2) * HW];
      float dxv = offb[(size_t)(dg * 18 + k * 2 + 1) * HW];
      float mv  = mb[(size_t)(dg * 9 + k) * HW];
      float py = (float)(y - 1 + k / 3) + dyv;
      float px = (float)(x - 1 + (k % 3)) + dxv;
      float y0f = floorf(py), x0f = floorf(px);
      float wy = py - y0f, wx = px - x0f;
      int yi = (int)y0f, xi = (int)x0f;
      bool vy0 = (yi >= 0) & (yi < Hh);
      bool vy1 = (yi + 1 >= 0) & (yi + 1 < Hh);
      bool vx0 = (xi >= 0) & (xi < Ww);
      bool vx1 = (xi + 1 >= 0) & (xi + 1 < Ww);
      int y0c = min(max(yi, 0), Hh - 1),  y1c = min(max(yi + 1, 0), Hh - 1);
      int x0c = min(max(xi, 0), Ww - 1),  x1c = min(max(xi + 1, 0), Ww - 1);
      float w00 = (vy0 && vx0) ? (1.f - wy) * (1.f - wx) : 0.f;
      float w01 = (vy0 && vx1) ? (1.f - wy) * wx : 0.f;
      float w10 = (vy1 && vx0) ? wy * (1.f - wx) : 0.f;
      float w11 = (vy1 && vx1) ? wy * wx : 0.f;
      float4 s00 = xp4[y0c * Ww + x0c];
      float4 s01 = xp4[y0c * Ww + x1c];
      float4 s10 = xp4[y1c * Ww + x0c];
      float4 s11 = xp4[y1c * Ww + x1c];
      float c0 = (s00.x * w00 + s01.x * w01 + s10.x * w10 + s11.x * w11) * mv;
      float c1 = (s00.y * w00 + s01.y * w01 + s10.y * w10 + s11.y * w11) * mv;
      float c2 = (s00.z * w00 + s01.z * w01 + s10.z * w10 + s11.z * w11) * mv;
      float c3 = (s00.w * w00 + s01.w * w01 + s10.w * w10 + s11.w * w11) * mv;
      const float* wp = wt + (size_t)(dg * 9 + k) * 256 + cog * 16;
      #pragma unroll
      for (int i = 0; i < 16; i++)
        acc[i] = fmaf(c0, wp[i],
                 fmaf(c1, wp[64 + i],
                 fmaf(c2, wp[128 + i],
                 fmaf(c3, wp[192 + i], acc[i]))));
    }
  }
  #pragma unroll
  for (int i = 0; i < 16; i++) {
    int co = cog * 16 + i;
    out[((size_t)b * 64 + co) * HW + p] = acc[i] + bias[co];
  }
}

// ---------------- launch ----------------
extern "C" void kernel_launch(void* const* d_in, const int* in_sizes, int n_in,
                              void* d_out, int out_size, void* d_ws, size_t ws_size,
                              hipStream_t stream) {
  const float* x    = (const float*)d_in[0];
  const float* cond = (const float*)d_in[1];
  const float* flow = (const float*)d_in[2];
  const float* w1 = (const float*)d_in[3];
  const float* b1 = (const float*)d_in[4];
  const float* w2 = (const float*)d_in[5];
  const float* b2 = (const float*)d_in[6];
  const float* w3 = (const float*)d_in[7];
  const float* b3 = (const float*)d_in[8];
  const float* w4 = (const float*)d_in[9];
  const float* b4 = (const float*)d_in[10];
  const float* wD = (const float*)d_in[11];
  const float* bD = (const float*)d_in[12];
  float* out = (float*)d_out;
  const int B = 2;

  float* ws = (float*)d_ws;
  float* h1   = ws;                          // 2*64*HW
  float* h2   = h1 + (size_t)2 * 64 * HW;    // 2*64*HW
  float* offb = h2 + (size_t)2 * 64 * HW;    // 2*288*HW
  float* mskb = offb + (size_t)2 * 288 * HW; // 2*144*HW
  float* xt   = mskb + (size_t)2 * 144 * HW; // 2*64*HW (float4 layout)
  float* wt1  = xt + (size_t)2 * 64 * HW;    // 133*9*64
  float* wt2  = wt1 + 133 * 9 * 64;          // 64*9*64
  float* wt3  = wt2 + 64 * 9 * 64;           // 64*9*64
  float* wt4  = wt3 + 64 * 9 * 64;           // 64*9*432
  float* wtd  = wt4 + (size_t)64 * 9 * 432;  // 16*9*4*64

  wtrans_conv_k<<<dim3((64 * 133 * 9 + 255) / 256), 256, 0, stream>>>(w1, wt1, 64, 133);
  wtrans_conv_k<<<dim3((64 * 64 * 9 + 255) / 256), 256, 0, stream>>>(w2, wt2, 64, 64);
  wtrans_conv_k<<<dim3((64 * 64 * 9 + 255) / 256), 256, 0, stream>>>(w3, wt3, 64, 64);
  wtrans_conv_k<<<dim3((432 * 64 * 9 + 255) / 256), 256, 0, stream>>>(w4, wt4, 432, 64);
  wtrans_dcn_k<<<dim3((64 * 64 * 9 + 255) / 256), 256, 0, stream>>>(wD, wtd);
  xtrans_k<<<dim3(B * 16 * HW / 256), 256, 0, stream>>>(x, xt, B);

  dim3 blk(16, 16);
  conv3x3_k<133, 7, 0><<<dim3(8, 8, B * 4),  blk, 0, stream>>>(cond, wt1, b1, h1, nullptr, nullptr, 64, 4);
  conv3x3_k<64,  8, 0><<<dim3(8, 8, B * 4),  blk, 0, stream>>>(h1, wt2, b2, h2, nullptr, nullptr, 64, 4);
  conv3x3_k<64,  8, 0><<<dim3(8, 8, B * 4),  blk, 0, stream>>>(h2, wt3, b3, h1, nullptr, nullptr, 64, 4);
  conv3x3_k<64,  8, 2><<<dim3(8, 8, B * 27), blk, 0, stream>>>(h1, wt4, b4, offb, mskb, flow, 432, 27);
  dcn_k<<<dim3(8, 8, B * 4), blk, 0, stream>>>(xt, offb, mskb, wtd, bD, out);
}

// Round 2
// 392.441 us; speedup vs baseline: 2.1323x; 2.1323x over previous
//
#include <hip/hip_runtime.h>
#include <math.h>

#define Hh 128
#define Ww 128
#define HW (128*128)

typedef unsigned short u16;
typedef unsigned int uint;
typedef __attribute__((ext_vector_type(8))) short short8;
typedef __attribute__((ext_vector_type(4))) float f32x4;

__device__ inline u16 bf16_rne(float v) {
  uint x = __float_as_uint(v);
  uint r = (x + 0x7fffu + ((x >> 16) & 1u)) >> 16;
  return (u16)r;
}
__device__ inline float bf16f(u16 u) { return __uint_as_float(((uint)u) << 16); }

// ---------------- prep: cond [B][133][HW] f32 -> [B][HW][320] u16 (2c+part), pad to 160 ci
__global__ __launch_bounds__(256) void prep_cond_k(const float* __restrict__ cond,
                                                   u16* __restrict__ out) {
  int p = blockIdx.x * 256 + threadIdx.x;
  int b = blockIdx.y;
  const float* cb = cond + (size_t)b * 133 * HW + p;
  u16* ob = out + ((size_t)b * HW + p) * 320;
  for (int c = 0; c < 160; c += 4) {
    u16 buf[8];
    #pragma unroll
    for (int j = 0; j < 4; j++) {
      float v = (c + j < 133) ? cb[(size_t)(c + j) * HW] : 0.f;
      u16 hi = bf16_rne(v);
      buf[2 * j] = hi;
      buf[2 * j + 1] = bf16_rne(v - bf16f(hi));
    }
    *(uint4*)&ob[c * 2] = *(uint4*)buf;
  }
}

// ---------------- weight -> MFMA A-fragment layout
// frag id = ((t*NC + c)*2 + P)*NCOF + f ; 64 lanes x 8 bf16 (1KB)
__global__ __launch_bounds__(256) void wtrans_mfma_k(const float* __restrict__ w,
                                                     u16* __restrict__ wt,
                                                     int CIN, int NC, int NCOF) {
  int idx = blockIdx.x * 256 + threadIdx.x;
  int total = 9 * NC * 2 * NCOF * 64;
  if (idx >= total) return;
  int lane = idx & 63;
  int frag = idx >> 6;
  int f = frag % NCOF;
  int rest = frag / NCOF;
  int P = rest & 1; rest >>= 1;
  int c = rest % NC;
  int t = rest / NC;
  int co = f * 16 + (lane & 15);
  int ci0 = c * 32 + (lane >> 4) * 8;
  u16 buf[8];
  #pragma unroll
  for (int j = 0; j < 8; j++) {
    int ci = ci0 + j;
    float v = (ci < CIN) ? w[((size_t)co * CIN + ci) * 9 + t] : 0.f;
    u16 hi = bf16_rne(v);
    buf[j] = P ? bf16_rne(v - bf16f(hi)) : hi;
  }
  *(uint4*)&wt[(size_t)idx * 8] = *(uint4*)buf;
}

// dcn weight [64][64][3][3] -> [dg][k][c][64]
__global__ __launch_bounds__(256) void wtrans_dcn_k(const float* __restrict__ w,
                                                    float* __restrict__ wt) {
  int idx = blockIdx.x * 256 + threadIdx.x;
  if (idx >= 64 * 64 * 9) return;
  int co = idx / 576;
  int r = idx % 576;
  int ci = r / 9, k = r % 9;
  int dg = ci >> 2, c = ci & 3;
  wt[(((size_t)dg * 9 + k) * 4 + c) * 64 + co] = w[idx];
}

// x [B][64][H][W] -> xt [B][16][H][W][4]
__global__ __launch_bounds__(256) void xtrans_k(const float* __restrict__ x,
                                                float* __restrict__ xt, int B) {
  int idx = blockIdx.x * 256 + threadIdx.x;
  int total = B * 16 * HW;
  if (idx >= total) return;
  int b = idx / (16 * HW);
  int r = idx % (16 * HW);
  int dg = r / HW, p = r % HW;
  const float* xb = x + ((size_t)b * 64 + dg * 4) * HW + p;
  float4 v;
  v.x = xb[0]; v.y = xb[HW]; v.z = xb[2 * HW]; v.w = xb[3 * HW];
  ((float4*)xt)[idx] = v;
}

// ---------------- conv3x3 via MFMA, 3-term bf16 split ----------------
// in_hl: [B][HW][2*CINP] u16 interleaved (hi,lo). Tile 16x16 px, 4 waves (one px-row-quad each).
// LDS per round: one 32-ci chunk, both parts: [2][18][18][40] u16.
template<int CINP, int NC, int NCF, int NCOF, int EPI>
__global__ __launch_bounds__(256) void conv_mfma_k(
    const u16* __restrict__ in_hl, const u16* __restrict__ wt,
    const float* __restrict__ bias,
    u16* __restrict__ out_hl,
    float* __restrict__ offb, float* __restrict__ mskb,
    const float* __restrict__ flow, int cogroups)
{
  constexpr int C2 = 2 * CINP;
  __shared__ u16 lds[2 * 18 * 18 * 40];
  const int tid = threadIdx.x;
  const int lane = tid & 63, wave = tid >> 6;
  const int b = blockIdx.z / cogroups, cog = blockIdx.z % cogroups;
  const int gx0 = blockIdx.x * 16, gy0 = blockIdx.y * 16;

  f32x4 acc[4][NCF];
  #pragma unroll
  for (int i = 0; i < 4; i++)
    #pragma unroll
    for (int j = 0; j < NCF; j++) acc[i][j] = (f32x4)0.f;

  const u16* inb = in_hl + (size_t)b * HW * C2;

  for (int c = 0; c < NC; c++) {
    __syncthreads();
    // stage 18x18 halo, ci chunk c (32 ci), de-interleave hi/lo
    for (int i = tid; i < 2592; i += 256) {
      int px = i >> 3, q = i & 7;
      int py = px / 18, pxx = px - py * 18;
      int gy = gy0 - 1 + py, gx = gx0 - 1 + pxx;
      uint4 v = make_uint4(0, 0, 0, 0);
      if (gy >= 0 && gy < Hh && gx >= 0 && gx < Ww)
        v = *(const uint4*)&inb[(size_t)(gy * Ww + gx) * C2 + (c * 32 + q * 4) * 2];
      uint h0 = (v.x & 0xffffu) | (v.y << 16);
      uint h1 = (v.z & 0xffffu) | (v.w << 16);
      uint l0 = (v.x >> 16) | (v.y & 0xffff0000u);
      uint l1 = (v.z >> 16) | (v.w & 0xffff0000u);
      int base = (py * 18 + pxx) * 40 + q * 4;
      *(uint2*)&lds[base] = make_uint2(h0, h1);
      *(uint2*)&lds[12960 + base] = make_uint2(l0, l1);
    }
    __syncthreads();

    int dy = 0, dx = 0;
    for (int tap = 0; tap < 9; tap++) {
      short8 bh[4], bl[4];
      #pragma unroll
      for (int pl = 0; pl < 4; pl++) {
        int addr = ((wave * 4 + pl + dy) * 18 + dx + (lane & 15)) * 40 + (lane >> 4) * 8;
        bh[pl] = *(const short8*)&lds[addr];
        bl[pl] = *(const short8*)&lds[12960 + addr];
      }
      // pass 0: hi x WH, 1: lo x WH, 2: hi x WL
      #pragma unroll
      for (int pass = 0; pass < 3; pass++) {
        const int P = (pass == 2) ? 1 : 0;
        const size_t fb = (((size_t)(tap * NC + c) * 2 + P) * NCOF + cog * NCF) * 512
                          + (size_t)lane * 8;
        #pragma unroll
        for (int cf = 0; cf < NCF; cf++) {
          short8 a = *(const short8*)&wt[fb + (size_t)cf * 512];
          #pragma unroll
          for (int pl = 0; pl < 4; pl++) {
            acc[pl][cf] = __builtin_amdgcn_mfma_f32_16x16x32_bf16(
                a, (pass == 1) ? bl[pl] : bh[pl], acc[pl][cf], 0, 0, 0);
          }
        }
      }
      dx++; if (dx == 3) { dx = 0; dy++; }
    }
  }

  const int px = gx0 + (lane & 15);
  const int co_l = (lane >> 4) * 4;
  if (EPI == 0) {
    #pragma unroll
    for (int pl = 0; pl < 4; pl++) {
      size_t pix = (size_t)(gy0 + wave * 4 + pl) * Ww + px;
      #pragma unroll
      for (int cf = 0; cf < NCF; cf++) {
        int c0 = (cog * NCF + cf) * 16 + co_l;
        u16 buf[8];
        #pragma unroll
        for (int r = 0; r < 4; r++) {
          float v = acc[pl][cf][r] + bias[c0 + r];
          v = (v >= 0.f) ? v : 0.1f * v;
          u16 hi = bf16_rne(v);
          buf[2 * r] = hi;
          buf[2 * r + 1] = bf16_rne(v - bf16f(hi));
        }
        *(uint4*)&out_hl[((size_t)b * HW + pix) * 128 + (size_t)c0 * 2] = *(uint4*)buf;
      }
    }
  } else {
    #pragma unroll
    for (int pl = 0; pl < 4; pl++) {
      size_t pix = (size_t)(gy0 + wave * 4 + pl) * Ww + px;
      float fl0 = flow[((size_t)b * 2 + 0) * HW + pix];
      float fl1 = flow[((size_t)b * 2 + 1) * HW + pix];
      #pragma unroll
      for (int cf = 0; cf < NCF; cf++) {
        int c0 = (cog * NCF + cf) * 16 + co_l;
        #pragma unroll
        for (int r = 0; r < 4; r++) {
          int cc = c0 + r;
          float v = acc[pl][cf][r] + bias[cc];
          if (cc < 288) {
            float e = __expf(2.f * v);
            float t = 1.f - 2.f * __builtin_amdgcn_rcpf(e + 1.f);
            offb[((size_t)b * 288 + cc) * HW + pix] = 10.f * t + ((cc & 1) ? fl0 : fl1);
          } else {
            mskb[((size_t)b * 144 + (cc - 288)) * HW + pix] =
                __builtin_amdgcn_rcpf(1.f + __expf(-v));
          }
        }
      }
    }
  }
}

// ---------------- modulated deformable conv (partials over dg halves) ----------------
__global__ __launch_bounds__(256) void dcn_k(
    const float* __restrict__ xt, const float* __restrict__ off,
    const float* __restrict__ msk, const float* __restrict__ wtd,
    float* __restrict__ part)
{
  const int tx = threadIdx.x, ty = threadIdx.y;
  const int bz = blockIdx.z;
  const int b = bz >> 3, cog = (bz >> 1) & 3, dgs = bz & 1;
  const int x = blockIdx.x * 16 + tx, y = blockIdx.y * 16 + ty;
  const int p = y * Ww + x;
  const float* offb = off + (size_t)b * 288 * HW + p;
  const float* mb = msk + (size_t)b * 144 * HW + p;

  float acc[16];
  #pragma unroll
  for (int i = 0; i < 16; i++) acc[i] = 0.f;

  for (int dgi = 0; dgi < 8; ++dgi) {
    int dg = dgs * 8 + dgi;
    const float4* xp4 = (const float4*)xt + (size_t)(b * 16 + dg) * HW;
    #pragma unroll
    for (int k = 0; k < 9; k++) {
      float dyv = offb[(size_t)(dg * 18 + k * 2) * HW];
      float dxv = offb[(size_t)(dg * 18 + k * 2 + 1) * HW];
      float mv = mb[(size_t)(dg * 9 + k) * HW];
      float py = (float)(y - 1 + k / 3) + dyv;
      float px = (float)(x - 1 + (k % 3)) + dxv;
      float y0f = floorf(py), x0f = floorf(px);
      float wy = py - y0f, wx = px - x0f;
      int yi = (int)y0f, xi = (int)x0f;
      bool vy0 = (yi >= 0) & (yi < Hh);
      bool vy1 = (yi + 1 >= 0) & (yi + 1 < Hh);
      bool vx0 = (xi >= 0) & (xi < Ww);
      bool vx1 = (xi + 1 >= 0) & (xi + 1 < Ww);
      int y0c = min(max(yi, 0), Hh - 1), y1c = min(max(yi + 1, 0), Hh - 1);
      int x0c = min(max(xi, 0), Ww - 1), x1c = min(max(xi + 1, 0), Ww - 1);
      float w00 = (vy0 && vx0) ? (1.f - wy) * (1.f - wx) : 0.f;
      float w01 = (vy0 && vx1) ? (1.f - wy) * wx : 0.f;
      float w10 = (vy1 && vx0) ? wy * (1.f - wx) : 0.f;
      float w11 = (vy1 && vx1) ? wy * wx : 0.f;
      float4 s00 = xp4[y0c * Ww + x0c];
      float4 s01 = xp4[y0c * Ww + x1c];
      float4 s10 = xp4[y1c * Ww + x0c];
      float4 s11 = xp4[y1c * Ww + x1c];
      float c0 = (s00.x * w00 + s01.x * w01 + s10.x * w10 + s11.x * w11) * mv;
      float c1 = (s00.y * w00 + s01.y * w01 + s10.y * w10 + s11.y * w11) * mv;
      float c2 = (s00.z * w00 + s01.z * w01 + s10.z * w10 + s11.z * w11) * mv;
      float c3 = (s00.w * w00 + s01.w * w01 + s10.w * w10 + s11.w * w11) * mv;
      const float* wp = wtd + (size_t)(dg * 9 + k) * 256 + cog * 16;
      #pragma unroll
      for (int i = 0; i < 16; i++)
        acc[i] = fmaf(c0, wp[i],
                 fmaf(c1, wp[64 + i],
                 fmaf(c2, wp[128 + i],
                 fmaf(c3, wp[192 + i], acc[i]))));
    }
  }
  float* pb = part + (((size_t)dgs * 2 + b) * 64 + cog * 16) * HW + p;
  #pragma unroll
  for (int i = 0; i < 16; i++) pb[(size_t)i * HW] = acc[i];
}

__global__ __launch_bounds__(256) void dcn_reduce_k(const float* __restrict__ part,
                                                    const float* __restrict__ bias,
                                                    float* __restrict__ out) {
  size_t e = ((size_t)blockIdx.x * 256 + threadIdx.x) * 4;  // over B*64*HW, exact
  int c = (int)((e / HW) & 63);
  const size_t stride = (size_t)128 * HW;
  float4 s0 = *(const float4*)&part[e];
  float4 s1 = *(const float4*)&part[stride + e];
  float bb = bias[c];
  float4 r;
  r.x = s0.x + s1.x + bb;
  r.y = s0.y + s1.y + bb;
  r.z = s0.z + s1.z + bb;
  r.w = s0.w + s1.w + bb;
  *(float4*)&out[e] = r;
}

// ---------------- launch ----------------
extern "C" void kernel_launch(void* const* d_in, const int* in_sizes, int n_in,
                              void* d_out, int out_size, void* d_ws, size_t ws_size,
                              hipStream_t stream) {
  const float* x    = (const float*)d_in[0];
  const float* cond = (const float*)d_in[1];
  const float* flow = (const float*)d_in[2];
  const float* w1 = (const float*)d_in[3];
  const float* b1 = (const float*)d_in[4];
  const float* w2 = (const float*)d_in[5];
  const float* b2 = (const float*)d_in[6];
  const float* w3 = (const float*)d_in[7];
  const float* b3 = (const float*)d_in[8];
  const float* w4 = (const float*)d_in[9];
  const float* b4 = (const float*)d_in[10];
  const float* wD = (const float*)d_in[11];
  const float* bD = (const float*)d_in[12];
  float* out = (float*)d_out;
  const int B = 2;

  char* ws = (char*)d_ws;
  u16*   cond_hl = (u16*)ws;                     // 20,971,520 B (aliased by part)
  float* part    = (float*)ws;                   // 16,777,216 B (after conv1 done)
  char* pw = ws + 20971520;
  u16*   hA   = (u16*)pw;            pw += 8388608;
  u16*   hB   = (u16*)pw;            pw += 8388608;
  float* offb = (float*)pw;          pw += 37748736;
  float* mskb = (float*)pw;          pw += 18874368;
  float* xt   = (float*)pw;          pw += 8388608;
  u16*   wt1  = (u16*)pw;            pw += 368640;
  u16*   wt2  = (u16*)pw;            pw += 147456;
  u16*   wt3  = (u16*)pw;            pw += 147456;
  u16*   wt4  = (u16*)pw;            pw += 995328;
  float* wtd  = (float*)pw;          pw += 147456;

  // prep + weight transposes
  prep_cond_k<<<dim3(HW / 256, B), 256, 0, stream>>>(cond, cond_hl);
  xtrans_k<<<dim3(B * 16 * HW / 256), 256, 0, stream>>>(x, xt, B);
  wtrans_mfma_k<<<dim3((9 * 5 * 2 * 4 * 64 + 255) / 256), 256, 0, stream>>>(w1, wt1, 133, 5, 4);
  wtrans_mfma_k<<<dim3((9 * 2 * 2 * 4 * 64 + 255) / 256), 256, 0, stream>>>(w2, wt2, 64, 2, 4);
  wtrans_mfma_k<<<dim3((9 * 2 * 2 * 4 * 64 + 255) / 256), 256, 0, stream>>>(w3, wt3, 64, 2, 4);
  wtrans_mfma_k<<<dim3((9 * 2 * 2 * 27 * 64 + 255) / 256), 256, 0, stream>>>(w4, wt4, 64, 2, 27);
  wtrans_dcn_k<<<dim3((64 * 64 * 9 + 255) / 256), 256, 0, stream>>>(wD, wtd);

  // convs (MFMA)
  conv_mfma_k<160, 5, 2, 4, 0><<<dim3(8, 8, B * 2), 256, 0, stream>>>(
      cond_hl, wt1, b1, hA, nullptr, nullptr, nullptr, 2);
  conv_mfma_k<64, 2, 2, 4, 0><<<dim3(8, 8, B * 2), 256, 0, stream>>>(
      hA, wt2, b2, hB, nullptr, nullptr, nullptr, 2);
  conv_mfma_k<64, 2, 2, 4, 0><<<dim3(8, 8, B * 2), 256, 0, stream>>>(
      hB, wt3, b3, hA, nullptr, nullptr, nullptr, 2);
  conv_mfma_k<64, 2, 3, 27, 2><<<dim3(8, 8, B * 9), 256, 0, stream>>>(
      hA, wt4, b4, nullptr, offb, mskb, flow, 9);

  // deformable conv: partials over {dg half} x {16-cout group}, then reduce + bias
  dcn_k<<<dim3(8, 8, B * 8), dim3(16, 16), 0, stream>>>(xt, offb, mskb, wtd, part);
  dcn_reduce_k<<<dim3(B * 64 * HW / 1024), 256, 0, stream>>>(part, bD, out);
}

// Round 3
// 279.563 us; speedup vs baseline: 2.9933x; 1.4038x over previous
//
#include <hip/hip_runtime.h>
#include <math.h>

#define Hh 128
#define Ww 128
#define HW (128*128)

typedef unsigned short u16;
typedef unsigned int uint;
typedef __attribute__((ext_vector_type(8))) short short8;
typedef __attribute__((ext_vector_type(4))) float f32x4;

__device__ inline u16 bf16_rne(float v) {
  uint x = __float_as_uint(v);
  uint r = (x + 0x7fffu + ((x >> 16) & 1u)) >> 16;
  return (u16)r;
}
__device__ inline float bf16f(u16 u) { return __uint_as_float(((uint)u) << 16); }

// ---------------- prep: cond [B][133][HW] f32 -> [B][HW][320] u16 (2c+part), pad to 160 ci
__global__ __launch_bounds__(256) void prep_cond_k(const float* __restrict__ cond,
                                                   u16* __restrict__ out) {
  int p = blockIdx.x * 256 + threadIdx.x;
  int b = blockIdx.y;
  const float* cb = cond + (size_t)b * 133 * HW + p;
  u16* ob = out + ((size_t)b * HW + p) * 320;
  for (int c = 0; c < 160; c += 4) {
    u16 buf[8];
    #pragma unroll
    for (int j = 0; j < 4; j++) {
      float v = (c + j < 133) ? cb[(size_t)(c + j) * HW] : 0.f;
      u16 hi = bf16_rne(v);
      buf[2 * j] = hi;
      buf[2 * j + 1] = bf16_rne(v - bf16f(hi));
    }
    *(uint4*)&ob[c * 2] = *(uint4*)buf;
  }
}

// ---------------- conv weight -> MFMA A-fragment layout
// frag id = ((t*NC + c)*2 + P)*NCOF + f ; 64 lanes x 8 bf16 (1KB)
__global__ __launch_bounds__(256) void wtrans_mfma_k(const float* __restrict__ w,
                                                     u16* __restrict__ wt,
                                                     int CIN, int NC, int NCOF) {
  int idx = blockIdx.x * 256 + threadIdx.x;
  int total = 9 * NC * 2 * NCOF * 64;
  if (idx >= total) return;
  int lane = idx & 63;
  int frag = idx >> 6;
  int f = frag % NCOF;
  int rest = frag / NCOF;
  int P = rest & 1; rest >>= 1;
  int c = rest % NC;
  int t = rest / NC;
  int co = f * 16 + (lane & 15);
  int ci0 = c * 32 + (lane >> 4) * 8;
  u16 buf[8];
  #pragma unroll
  for (int j = 0; j < 8; j++) {
    int ci = ci0 + j;
    float v = (ci < CIN) ? w[((size_t)co * CIN + ci) * 9 + t] : 0.f;
    u16 hi = bf16_rne(v);
    buf[j] = P ? bf16_rne(v - bf16f(hi)) : hi;
  }
  *(uint4*)&wt[(size_t)idx * 8] = *(uint4*)buf;
}

// ---------------- dcn weight [64co][64ci][3][3] -> A-frags over K=576 (ci = k*64 + dg*4 + c)
// frag id = chunk*8 + P*4 + f ; lane: co = f*16+(lane&15), ci0 = chunk*32+(lane>>4)*8
__global__ __launch_bounds__(256) void wtrans_dcn_mfma_k(const float* __restrict__ w,
                                                         u16* __restrict__ wt) {
  int idx = blockIdx.x * 256 + threadIdx.x;
  if (idx >= 18 * 2 * 4 * 64) return;
  int lane = idx & 63;
  int frag = idx >> 6;
  int f = frag & 3;
  int P = (frag >> 2) & 1;
  int chunk = frag >> 3;
  int co = f * 16 + (lane & 15);
  int ci0 = chunk * 32 + (lane >> 4) * 8;
  u16 buf[8];
  #pragma unroll
  for (int j = 0; j < 8; j++) {
    int ci = ci0 + j;
    int k = ci >> 6, cig = ci & 63;
    float v = w[((size_t)co * 64 + cig) * 9 + k];
    u16 hi = bf16_rne(v);
    buf[j] = P ? bf16_rne(v - bf16f(hi)) : hi;
  }
  *(uint4*)&wt[(size_t)idx * 8] = *(uint4*)buf;
}

// x [B][64][H][W] -> xt [B][16][H][W][4]
__global__ __launch_bounds__(256) void xtrans_k(const float* __restrict__ x,
                                                float* __restrict__ xt, int B) {
  int idx = blockIdx.x * 256 + threadIdx.x;
  int total = B * 16 * HW;
  if (idx >= total) return;
  int b = idx / (16 * HW);
  int r = idx % (16 * HW);
  int dg = r / HW, p = r % HW;
  const float* xb = x + ((size_t)b * 64 + dg * 4) * HW + p;
  float4 v;
  v.x = xb[0]; v.y = xb[HW]; v.z = xb[2 * HW]; v.w = xb[3 * HW];
  ((float4*)xt)[idx] = v;
}

// ---------------- conv3x3 via MFMA, 3-term bf16 split ----------------
template<int CINP, int NC, int NCF, int NCOF, int EPI>
__global__ __launch_bounds__(256) void conv_mfma_k(
    const u16* __restrict__ in_hl, const u16* __restrict__ wt,
    const float* __restrict__ bias,
    u16* __restrict__ out_hl,
    float* __restrict__ offb, float* __restrict__ mskb,
    const float* __restrict__ flow, int cogroups)
{
  constexpr int C2 = 2 * CINP;
  __shared__ u16 lds[2 * 18 * 18 * 40];
  const int tid = threadIdx.x;
  const int lane = tid & 63, wave = tid >> 6;
  const int b = blockIdx.z / cogroups, cog = blockIdx.z % cogroups;
  const int gx0 = blockIdx.x * 16, gy0 = blockIdx.y * 16;

  f32x4 acc[4][NCF];
  #pragma unroll
  for (int i = 0; i < 4; i++)
    #pragma unroll
    for (int j = 0; j < NCF; j++) acc[i][j] = (f32x4)0.f;

  const u16* inb = in_hl + (size_t)b * HW * C2;

  for (int c = 0; c < NC; c++) {
    __syncthreads();
    for (int i = tid; i < 2592; i += 256) {
      int px = i >> 3, q = i & 7;
      int py = px / 18, pxx = px - py * 18;
      int gy = gy0 - 1 + py, gx = gx0 - 1 + pxx;
      uint4 v = make_uint4(0, 0, 0, 0);
      if (gy >= 0 && gy < Hh && gx >= 0 && gx < Ww)
        v = *(const uint4*)&inb[(size_t)(gy * Ww + gx) * C2 + (c * 32 + q * 4) * 2];
      uint h0 = (v.x & 0xffffu) | (v.y << 16);
      uint h1 = (v.z & 0xffffu) | (v.w << 16);
      uint l0 = (v.x >> 16) | (v.y & 0xffff0000u);
      uint l1 = (v.z >> 16) | (v.w & 0xffff0000u);
      int base = (py * 18 + pxx) * 40 + q * 4;
      *(uint2*)&lds[base] = make_uint2(h0, h1);
      *(uint2*)&lds[12960 + base] = make_uint2(l0, l1);
    }
    __syncthreads();

    int dy = 0, dx = 0;
    for (int tap = 0; tap < 9; tap++) {
      short8 bh[4], bl[4];
      #pragma unroll
      for (int pl = 0; pl < 4; pl++) {
        int addr = ((wave * 4 + pl + dy) * 18 + dx + (lane & 15)) * 40 + (lane >> 4) * 8;
        bh[pl] = *(const short8*)&lds[addr];
        bl[pl] = *(const short8*)&lds[12960 + addr];
      }
      #pragma unroll
      for (int pass = 0; pass < 3; pass++) {
        const int P = (pass == 2) ? 1 : 0;
        const size_t fb = (((size_t)(tap * NC + c) * 2 + P) * NCOF + cog * NCF) * 512
                          + (size_t)lane * 8;
        #pragma unroll
        for (int cf = 0; cf < NCF; cf++) {
          short8 a = *(const short8*)&wt[fb + (size_t)cf * 512];
          #pragma unroll
          for (int pl = 0; pl < 4; pl++) {
            acc[pl][cf] = __builtin_amdgcn_mfma_f32_16x16x32_bf16(
                a, (pass == 1) ? bl[pl] : bh[pl], acc[pl][cf], 0, 0, 0);
          }
        }
      }
      dx++; if (dx == 3) { dx = 0; dy++; }
    }
  }

  const int px = gx0 + (lane & 15);
  const int co_l = (lane >> 4) * 4;
  if (EPI == 0) {
    #pragma unroll
    for (int pl = 0; pl < 4; pl++) {
      size_t pix = (size_t)(gy0 + wave * 4 + pl) * Ww + px;
      #pragma unroll
      for (int cf = 0; cf < NCF; cf++) {
        int c0 = (cog * NCF + cf) * 16 + co_l;
        u16 buf[8];
        #pragma unroll
        for (int r = 0; r < 4; r++) {
          float v = acc[pl][cf][r] + bias[c0 + r];
          v = (v >= 0.f) ? v : 0.1f * v;
          u16 hi = bf16_rne(v);
          buf[2 * r] = hi;
          buf[2 * r + 1] = bf16_rne(v - bf16f(hi));
        }
        *(uint4*)&out_hl[((size_t)b * HW + pix) * 128 + (size_t)c0 * 2] = *(uint4*)buf;
      }
    }
  } else {
    #pragma unroll
    for (int pl = 0; pl < 4; pl++) {
      size_t pix = (size_t)(gy0 + wave * 4 + pl) * Ww + px;
      float fl0 = flow[((size_t)b * 2 + 0) * HW + pix];
      float fl1 = flow[((size_t)b * 2 + 1) * HW + pix];
      #pragma unroll
      for (int cf = 0; cf < NCF; cf++) {
        int c0 = (cog * NCF + cf) * 16 + co_l;
        #pragma unroll
        for (int r = 0; r < 4; r++) {
          int cc = c0 + r;
          float v = acc[pl][cf][r] + bias[cc];
          if (cc < 288) {
            float e = __expf(2.f * v);
            float t = 1.f - 2.f * __builtin_amdgcn_rcpf(e + 1.f);
            offb[((size_t)b * 288 + cc) * HW + pix] = 10.f * t + ((cc & 1) ? fl0 : fl1);
          } else {
            mskb[((size_t)b * 144 + (cc - 288)) * HW + pix] =
                __builtin_amdgcn_rcpf(1.f + __expf(-v));
          }
        }
      }
    }
  }
}

// ---------------- dcn sampling: build bf16 im2col cols[b][18][px][32] ----------------
// ci = k*64 + dg*4 + c  ->  chunk = k*2 + (dg>=8), pos = (dg&7)*4 + c
__global__ __launch_bounds__(256) void dcn_sample_k(
    const float* __restrict__ xt, const float* __restrict__ off,
    const float* __restrict__ msk, u16* __restrict__ cols)
{
  const int tid = threadIdx.x;
  const int px = blockIdx.x * 256 + tid;
  const int b = blockIdx.y >> 4, dg = blockIdx.y & 15;
  const int y = px >> 7, x = px & 127;
  const float* offp = off + ((size_t)b * 288 + dg * 18) * HW + px;
  const float* mp   = msk + ((size_t)b * 144 + dg * 9) * HW + px;
  const float4* xp4 = (const float4*)xt + (size_t)(b * 16 + dg) * HW;
  const int s = dg >> 3;
  u16* cbase = cols + (size_t)b * 18 * HW * 32 + (size_t)px * 32 + (dg & 7) * 4;

  #pragma unroll
  for (int k = 0; k < 9; k++) {
    float dyv = offp[(size_t)(2 * k) * HW];
    float dxv = offp[(size_t)(2 * k + 1) * HW];
    float mv  = mp[(size_t)k * HW];
    float py = (float)(y - 1 + k / 3) + dyv;
    float pxx = (float)(x - 1 + (k % 3)) + dxv;
    float y0f = floorf(py), x0f = floorf(pxx);
    float wy = py - y0f, wx = px - x0f - (float)px + pxx - pxx;  // placeholder avoided below
    wx = pxx - x0f;
    int yi = (int)y0f, xi = (int)x0f;
    bool vy0 = (yi >= 0) & (yi < Hh);
    bool vy1 = (yi + 1 >= 0) & (yi + 1 < Hh);
    bool vx0 = (xi >= 0) & (xi < Ww);
    bool vx1 = (xi + 1 >= 0) & (xi + 1 < Ww);
    int y0c = min(max(yi, 0), Hh - 1), y1c = min(max(yi + 1, 0), Hh - 1);
    int x0c = min(max(xi, 0), Ww - 1), x1c = min(max(xi + 1, 0), Ww - 1);
    float w00 = (vy0 && vx0) ? (1.f - wy) * (1.f - wx) : 0.f;
    float w01 = (vy0 && vx1) ? (1.f - wy) * wx : 0.f;
    float w10 = (vy1 && vx0) ? wy * (1.f - wx) : 0.f;
    float w11 = (vy1 && vx1) ? wy * wx : 0.f;
    w00 *= mv; w01 *= mv; w10 *= mv; w11 *= mv;
    float4 s00 = xp4[y0c * Ww + x0c];
    float4 s01 = xp4[y0c * Ww + x1c];
    float4 s10 = xp4[y1c * Ww + x0c];
    float4 s11 = xp4[y1c * Ww + x1c];
    u16 buf[4];
    buf[0] = bf16_rne(s00.x * w00 + s01.x * w01 + s10.x * w10 + s11.x * w11);
    buf[1] = bf16_rne(s00.y * w00 + s01.y * w01 + s10.y * w10 + s11.y * w11);
    buf[2] = bf16_rne(s00.z * w00 + s01.z * w01 + s10.z * w10 + s11.z * w11);
    buf[3] = bf16_rne(s00.w * w00 + s01.w * w01 + s10.w * w10 + s11.w * w11);
    *(uint2*)&cbase[(size_t)(k * 2 + s) * HW * 32] = *(uint2*)buf;
  }
}

// ---------------- dcn GEMM: out[b,64co,px] = W[64,576] @ cols, 2-pass (WH, WL) ----------------
__global__ __launch_bounds__(256) void dcn_gemm_k(
    const u16* __restrict__ cols, const u16* __restrict__ wtd,
    const float* __restrict__ bias, float* __restrict__ out)
{
  const int tid = threadIdx.x;
  const int lane = tid & 63, wave = tid >> 6;
  const int b = blockIdx.x >> 8;
  const int px0 = (blockIdx.x & 255) * 64 + wave * 16;

  f32x4 acc[4];
  #pragma unroll
  for (int f = 0; f < 4; f++) acc[f] = (f32x4)0.f;

  const u16* cb = cols + (size_t)b * 18 * HW * 32
                  + ((size_t)px0 + (lane & 15)) * 32 + (lane >> 4) * 8;
  const u16* wb = wtd + (size_t)lane * 8;

  for (int ch = 0; ch < 18; ch++) {
    short8 bh = *(const short8*)&cb[(size_t)ch * HW * 32];
    const u16* wc = wb + (size_t)ch * 8 * 512;
    #pragma unroll
    for (int f = 0; f < 4; f++) {
      short8 aH = *(const short8*)&wc[(size_t)f * 512];
      short8 aL = *(const short8*)&wc[(size_t)(4 + f) * 512];
      acc[f] = __builtin_amdgcn_mfma_f32_16x16x32_bf16(aH, bh, acc[f], 0, 0, 0);
      acc[f] = __builtin_amdgcn_mfma_f32_16x16x32_bf16(aL, bh, acc[f], 0, 0, 0);
    }
  }

  const int pxo = px0 + (lane & 15);
  #pragma unroll
  for (int f = 0; f < 4; f++) {
    #pragma unroll
    for (int r = 0; r < 4; r++) {
      int co = f * 16 + (lane >> 4) * 4 + r;
      out[((size_t)b * 64 + co) * HW + pxo] = acc[f][r] + bias[co];
    }
  }
}

// ---------------- launch ----------------
extern "C" void kernel_launch(void* const* d_in, const int* in_sizes, int n_in,
                              void* d_out, int out_size, void* d_ws, size_t ws_size,
                              hipStream_t stream) {
  const float* x    = (const float*)d_in[0];
  const float* cond = (const float*)d_in[1];
  const float* flow = (const float*)d_in[2];
  const float* w1 = (const float*)d_in[3];
  const float* b1 = (const float*)d_in[4];
  const float* w2 = (const float*)d_in[5];
  const float* b2 = (const float*)d_in[6];
  const float* w3 = (const float*)d_in[7];
  const float* b3 = (const float*)d_in[8];
  const float* w4 = (const float*)d_in[9];
  const float* b4 = (const float*)d_in[10];
  const float* wD = (const float*)d_in[11];
  const float* bD = (const float*)d_in[12];
  float* out = (float*)d_out;
  const int B = 2;

  char* ws = (char*)d_ws;
  // cols aliases cond_hl+hA+hB (all dead by sample time): 37,748,736 B
  u16*   cols    = (u16*)ws;
  u16*   cond_hl = (u16*)ws;                 // 20,971,520 B
  u16*   hA   = (u16*)(ws + 20971520);       // 8,388,608 B
  u16*   hB   = (u16*)(ws + 29360128);       // 8,388,608 B
  char* pw = ws + 37748736;
  float* offb = (float*)pw;          pw += 37748736;
  float* mskb = (float*)pw;          pw += 18874368;
  float* xt   = (float*)pw;          pw += 8388608;
  u16*   wt1  = (u16*)pw;            pw += 368640;
  u16*   wt2  = (u16*)pw;            pw += 147456;
  u16*   wt3  = (u16*)pw;            pw += 147456;
  u16*   wt4  = (u16*)pw;            pw += 995328;
  u16*   wtd  = (u16*)pw;            pw += 147456;

  // prep + weight transposes
  prep_cond_k<<<dim3(HW / 256, B), 256, 0, stream>>>(cond, cond_hl);
  xtrans_k<<<dim3(B * 16 * HW / 256), 256, 0, stream>>>(x, xt, B);
  wtrans_mfma_k<<<dim3((9 * 5 * 2 * 4 * 64 + 255) / 256), 256, 0, stream>>>(w1, wt1, 133, 5, 4);
  wtrans_mfma_k<<<dim3((9 * 2 * 2 * 4 * 64 + 255) / 256), 256, 0, stream>>>(w2, wt2, 64, 2, 4);
  wtrans_mfma_k<<<dim3((9 * 2 * 2 * 4 * 64 + 255) / 256), 256, 0, stream>>>(w3, wt3, 64, 2, 4);
  wtrans_mfma_k<<<dim3((9 * 2 * 2 * 27 * 64 + 255) / 256), 256, 0, stream>>>(w4, wt4, 64, 2, 27);
  wtrans_dcn_mfma_k<<<dim3((18 * 2 * 4 * 64 + 255) / 256), 256, 0, stream>>>(wD, wtd);

  // convs (MFMA)
  conv_mfma_k<160, 5, 2, 4, 0><<<dim3(8, 8, B * 2), 256, 0, stream>>>(
      cond_hl, wt1, b1, hA, nullptr, nullptr, nullptr, 2);
  conv_mfma_k<64, 2, 2, 4, 0><<<dim3(8, 8, B * 2), 256, 0, stream>>>(
      hA, wt2, b2, hB, nullptr, nullptr, nullptr, 2);
  conv_mfma_k<64, 2, 2, 4, 0><<<dim3(8, 8, B * 2), 256, 0, stream>>>(
      hB, wt3, b3, hA, nullptr, nullptr, nullptr, 2);
  conv_mfma_k<64, 2, 3, 27, 2><<<dim3(8, 8, B * 9), 256, 0, stream>>>(
      hA, wt4, b4, nullptr, offb, mskb, flow, 9);

  // deformable conv: sample -> im2col (bf16) -> MFMA GEMM
  dcn_sample_k<<<dim3(HW / 256, B * 16), 256, 0, stream>>>(xt, offb, mskb, cols);
  dcn_gemm_k<<<dim3(512), 256, 0, stream>>>(cols, wtd, bD, out);
}